// Round 5
// baseline (379.725 us; speedup 1.0000x reference)
//
#include <hip/hip_runtime.h>

#define L 21
#define NVOX 4096
#define ITERS 5
#define NU 210      // monomials of degree <= 4 in 6 vars
#define UPAD 224    // padded rows (210..223 are zero)
#define NBLK (NU + L)   // 231 blocks: 210 g1 + 21 spatial
#define TPB 512

// ---------------------------------------------------------------------------
// Uncached (LLC coherence-point) scalar access via builtins — compiler tracks
// the data deps (no inline-asm races). Agent-scope relaxed ops bypass L1/L2.
// ---------------------------------------------------------------------------
__device__ __forceinline__ float uload(const float* p) {
    return __hip_atomic_load(p, __ATOMIC_RELAXED, __HIP_MEMORY_SCOPE_AGENT);
}
__device__ __forceinline__ void ustore(float* p, float v) {
    __hip_atomic_store(p, v, __ATOMIC_RELAXED, __HIP_MEMORY_SCOPE_AGENT);
}

// ---------------------------------------------------------------------------
// Grid barrier v2 — contention-sharded, all-relaxed.
//   arrival: 8 sub-counters (128B apart, <=32 RMWs each) -> 1 root (8 RMWs)
//   broadcast: root-finisher stores phase+1 to 16 gen shards (128B apart)
//   spin: each leader polls shard (bid&15) with s_sleep(4) pacing
// Data visibility: all cross-phase mutable data is written via write-through
// agent ops (ustore / device atomicAdd) and drained by vmcnt(0) BEFORE the
// arrival RMW -> already at the LLC coherence point when the barrier opens.
// Optional acquire fence (L1/L2 inv) only where the next phase CACHED-reads
// data rewritten last phase (q at the P3 -> next-P2 boundary).
//   Phi,nsp,cu,W1,W2 : LLC-written once at init, cached reads after (immutable)
//   q   : LLC-written (init + P3), CACHED reads in P2 -> inv at P3->P2 only
//   spv : LLC-written (P2), LLC-read (P3) — never dirty in L2
//   A2  : LLC-zeroed, device atomicAdd (P2), LLC-read (P3)
//   out : plain cached stores; flushed by end-of-dispatch release
// Layout in bar[] (uint32): sub[g] @ g*32 (g<8), root @ 320, gen[s] @ 384+s*32
// ---------------------------------------------------------------------------
__device__ __forceinline__ void gridbar(unsigned* bar, int phase, bool inv) {
    asm volatile("s_waitcnt vmcnt(0) lgkmcnt(0)" ::: "memory");
    __syncthreads();
    if (threadIdx.x == 0) {
        const int bid = blockIdx.x;
        const int g = bid >> 5;
        const unsigned gsz = (g == 7) ? (unsigned)(NBLK - 224) : 32u;
        unsigned o = __hip_atomic_fetch_add(&bar[g * 32], 1u, __ATOMIC_RELAXED,
                                            __HIP_MEMORY_SCOPE_AGENT);
        if (o % gsz == gsz - 1u) {
            unsigned r = __hip_atomic_fetch_add(&bar[320], 1u, __ATOMIC_RELAXED,
                                                __HIP_MEMORY_SCOPE_AGENT);
            if ((r & 7u) == 7u) {
#pragma unroll
                for (int s = 0; s < 16; s++)
                    __hip_atomic_store(&bar[384 + s * 32], (unsigned)(phase + 1),
                                       __ATOMIC_RELAXED, __HIP_MEMORY_SCOPE_AGENT);
            }
        }
        unsigned* myg = &bar[384 + (bid & 15) * 32];
        while (__hip_atomic_load(myg, __ATOMIC_RELAXED,
                                 __HIP_MEMORY_SCOPE_AGENT) < (unsigned)(phase + 1))
            __builtin_amdgcn_s_sleep(4);
        if (inv)
            __builtin_amdgcn_fence(__ATOMIC_ACQUIRE, "agent");
        asm volatile("" ::: "memory");
    }
    __syncthreads();
}

__global__ __launch_bounds__(TPB) void crf_fused(
    const float* __restrict__ img, const float* __restrict__ logits,
    const float* __restrict__ Wsp, const float* __restrict__ Wbi,
    const float* __restrict__ Wc,
    float* __restrict__ Phi, float* __restrict__ nsp, float* __restrict__ q,
    float* __restrict__ spv, float* __restrict__ A2,
    float* __restrict__ cu, float* __restrict__ W1, float* __restrict__ W2,
    unsigned* __restrict__ bar, float* __restrict__ out)
{
    __shared__ float smem[8208];   // spatial: 4096+4096+16; p3: 6041
    const int tid = threadIdx.x;
    const int bid = blockIdx.x;
    int phase = 0;

    // ---------------- INIT ----------------
    if (bid < 32) {
        // Phi builder: 128 voxels/block, 4 u-groups of 56
        const int vloc = tid & 127;
        const int w = tid >> 7;
        const int i = bid * 128 + vloc;
        const int z = i >> 8, yy = (i >> 4) & 15, xx = i & 15;
        const float ia = 1.0f / 67.0f, ib = 1.0f / 3.0f;
        float f[6];
        f[0] = (float)z * ia; f[1] = (float)yy * ia; f[2] = (float)xx * ia;
        f[3] = img[i] * ib; f[4] = img[NVOX + i] * ib; f[5] = img[2 * NVOX + i] * ib;
        float p[6][5];
#pragma unroll
        for (int c = 0; c < 6; c++) {
            p[c][0] = 1.f;
#pragma unroll
            for (int k = 1; k < 5; k++) p[c][k] = p[c][k - 1] * f[c];
        }
        float hsv = 0.5f * (f[0]*f[0] + f[1]*f[1] + f[2]*f[2] +
                            f[3]*f[3] + f[4]*f[4] + f[5]*f[5]);
        float e0 = __expf(-hsv);
        const int ulo = w * 56, uhi = ulo + 56;
        int u = 0;
        for (int a0 = 0; a0 <= 4; a0++)
        for (int a1 = 0; a1 <= 4 - a0; a1++)
        for (int a2 = 0; a2 <= 4 - a0 - a1; a2++)
        for (int a3 = 0; a3 <= 4 - a0 - a1 - a2; a3++)
        for (int a4 = 0; a4 <= 4 - a0 - a1 - a2 - a3; a4++)
        for (int a5 = 0; a5 <= 4 - a0 - a1 - a2 - a3 - a4; a5++) {
            if (u >= ulo && u < uhi)
                ustore(&Phi[(size_t)u * NVOX + i],
                       e0 * p[0][a0] * p[1][a1] * p[2][a2] * p[3][a3] * p[4][a4] * p[5][a5]);
            u++;
        }
        if (w == 3)
            for (int uz = NU; uz < UPAD; uz++)
                ustore(&Phi[(size_t)uz * NVOX + i], 0.f);
        if (w == 0) {
            float hz = 0.f, hy = 0.f, hx = 0.f;
            for (int t = 0; t < 16; t++) {
                float dz = (float)(z - t), dy = (float)(yy - t), dx = (float)(xx - t);
                hz += __expf(-0.5f * dz * dz);
                hy += __expf(-0.5f * dy * dy);
                hx += __expf(-0.5f * dx * dx);
            }
            ustore(&nsp[i], hz * hy * hx);
        }
        if (w == 1) {   // softmax of logits -> q (iteration 0)
            float vals[L]; float mx = -1e30f;
#pragma unroll
            for (int l = 0; l < L; l++) { vals[l] = logits[l * NVOX + i]; mx = fmaxf(mx, vals[l]); }
            float sum = 0.f;
#pragma unroll
            for (int l = 0; l < L; l++) { vals[l] = __expf(vals[l] - mx); sum += vals[l]; }
            float inv = 1.f / sum;
#pragma unroll
            for (int l = 0; l < L; l++) ustore(&q[l * NVOX + i], vals[l] * inv);
        }
    } else if (bid == 32) {
        for (int e = tid; e < L * L; e += TPB) {
            int r = e / L, c = e % L;
            float s1 = 0.f, s2 = 0.f;
            for (int k = 0; k < L; k++) {
                float wc = Wc[r * L + k];
                s1 = fmaf(wc, Wsp[k * L + c], s1);
                s2 = fmaf(wc, Wbi[k * L + c], s2);
            }
            ustore(&W1[e], s1); ustore(&W2[e], s2);
        }
        if (tid < 256) {
            const float invf[5] = {1.f, 1.f, 0.5f, 1.f / 6.f, 1.f / 24.f};
            float mine = 0.f;   // stays 0 for tid >= NU
            int v = 0;
            for (int a0 = 0; a0 <= 4; a0++)
            for (int a1 = 0; a1 <= 4 - a0; a1++)
            for (int a2 = 0; a2 <= 4 - a0 - a1; a2++)
            for (int a3 = 0; a3 <= 4 - a0 - a1 - a2; a3++)
            for (int a4 = 0; a4 <= 4 - a0 - a1 - a2 - a3; a4++)
            for (int a5 = 0; a5 <= 4 - a0 - a1 - a2 - a3 - a4; a5++) {
                if (v == tid)
                    mine = invf[a0] * invf[a1] * invf[a2] * invf[a3] * invf[a4] * invf[a5];
                v++;
            }
            ustore(&cu[tid], mine);
        }
    } else if (bid == 33) {
        // zero BOTH A2 double-buffers (22 rows each)
        for (int e = tid; e < 2 * 22 * UPAD; e += TPB) ustore(&A2[e], 0.f);
    }
    gridbar(bar, phase++, false);   // all init data at LLC; nothing stale cached

    // ---------------- ITERATIONS ----------------
    for (int it = 0; it < ITERS; it++) {
        float* A2cur  = A2 + (it & 1) * 22 * UPAD;
        float* A2next = A2 + ((it + 1) & 1) * 22 * UPAD;

        // ================= P2 =================
        if (bid < NU) {
            // g1 for u=bid: 8 waves x 512-voxel chunks, 22 accumulators.
            // q/Phi reads CACHED (q lines invalidated at the last barrier).
            const int lane = tid & 63, w = tid >> 6;
            const float4* Pr = (const float4*)(Phi + (size_t)bid * NVOX) + w * 128;
            float4 pa = Pr[lane];
            float4 pb = Pr[lane + 64];
            float acc[22];
            acc[21] = pa.x + pa.y + pa.z + pa.w + pb.x + pb.y + pb.z + pb.w;
#pragma unroll
            for (int m = 0; m < L; m++) {
                const float4* Qr = (const float4*)(q + m * NVOX) + w * 128;
                float4 qa = Qr[lane];
                float4 qb = Qr[lane + 64];
                acc[m] = fmaf(qa.x, pa.x, fmaf(qa.y, pa.y, fmaf(qa.z, pa.z,
                         fmaf(qa.w, pa.w, fmaf(qb.x, pb.x, fmaf(qb.y, pb.y,
                         fmaf(qb.z, pb.z, qb.w * pb.w)))))));
            }
#pragma unroll
            for (int off = 32; off >= 1; off >>= 1)
#pragma unroll
                for (int m = 0; m < 22; m++)
                    acc[m] += __shfl_xor(acc[m], off);
            if (lane < 22) {
                float val;
                if (lane < L) {
                    float dot = 0.f;
#pragma unroll
                    for (int m = 0; m < L; m++)
                        dot = fmaf(W2[lane * L + m], acc[m], dot);
                    val = cu[bid] * dot;
                } else {
                    val = cu[bid] * acc[21];
                }
                atomicAdd(&A2cur[lane * UPAD + bid], val);   // device-scope, at LLC
            }
        } else {
            // spatial filter for label l = bid - NU (exact separable 16-tap)
            const int l = bid - NU;
            float* buf = smem;
            float* tmp = smem + 4096;
            float* g   = smem + 8192;
            if (tid < 16) g[tid] = __expf(-0.5f * (float)(tid * tid));
            for (int k = 0; k < 8; k++)
                buf[tid + TPB * k] = q[l * NVOX + tid + TPB * k];   // cached
            __syncthreads();
            for (int k = 0; k < 8; k++) {
                int idx = tid + TPB * k;
                int x = idx & 15, base = idx & ~15;
                float ssum = 0.f;
#pragma unroll
                for (int t = 0; t < 16; t++) {
                    int d = x - t; d = d < 0 ? -d : d;
                    ssum += g[d] * buf[base + t];
                }
                tmp[idx] = ssum;
            }
            __syncthreads();
            for (int k = 0; k < 8; k++) {
                int idx = tid + TPB * k;
                int y = (idx >> 4) & 15, base = idx & ~(15 << 4);
                float ssum = 0.f;
#pragma unroll
                for (int t = 0; t < 16; t++) {
                    int d = y - t; d = d < 0 ? -d : d;
                    ssum += g[d] * tmp[base + (t << 4)];
                }
                buf[idx] = ssum;
            }
            __syncthreads();
            for (int k = 0; k < 8; k++) {
                int idx = tid + TPB * k;
                int z = idx >> 8, base = idx & 255;
                float ssum = 0.f;
#pragma unroll
                for (int t = 0; t < 16; t++) {
                    int d = z - t; d = d < 0 ? -d : d;
                    ssum += g[d] * buf[base + (t << 8)];
                }
                ustore(&spv[l * NVOX + idx], ssum);   // write-through to LLC
            }
        }
        gridbar(bar, phase++, false);   // P3 reads spv/A2 at LLC -> no inv needed

        // ================= P3 =================
        if (bid < 128) {
            float* sA   = smem;                 // 21*224 = 4704
            float* sN   = smem + 4704;          // 224
            float* sw1  = smem + 4928;          // 441
            float* sspn = smem + 5369;          // 32*21 = 672, layout [v][m]
            const int vv = tid >> 4;            // 0..31 voxels
            const int s  = tid & 15;            // 0..15 u-splits (in-wave)
            const int i16 = bid * 32 + vv;
            for (int e = tid; e < L * UPAD; e += TPB) sA[e] = uload(&A2cur[e]);
            for (int e = tid; e < UPAD; e += TPB) sN[e] = uload(&A2cur[L * UPAD + e]);
            for (int e = tid; e < L * L; e += TPB) sw1[e] = W1[e];       // cached
            for (int e = tid; e < 32 * L; e += TPB) {
                int m = e >> 5, v2 = e & 31;
                sspn[v2 * L + m] = uload(&spv[m * NVOX + bid * 32 + v2])
                                   / nsp[bid * 32 + v2];                 // nsp cached
            }
            __syncthreads();
            float acc[22];
#pragma unroll
            for (int m = 0; m < 22; m++) acc[m] = 0.f;
            const int u0 = s * 14;
            for (int uu = 0; uu < 14; uu++) {
                float pv = Phi[(size_t)(u0 + uu) * NVOX + i16];   // cached
#pragma unroll
                for (int m = 0; m < L; m++)
                    acc[m] = fmaf(sA[m * UPAD + u0 + uu], pv, acc[m]);
                acc[21] = fmaf(sN[u0 + uu], pv, acc[21]);
            }
            // butterfly allreduce across the 16 u-splits (within wave)
#pragma unroll
            for (int off = 1; off <= 8; off <<= 1)
#pragma unroll
                for (int m = 0; m < 22; m++)
                    acc[m] += __shfl_xor(acc[m], off);
            float rbi = 1.f / acc[21];
            float r[L];
#pragma unroll
            for (int l = 0; l < L; l++) {
                float v = acc[l] * rbi;
#pragma unroll
                for (int m = 0; m < L; m++)
                    v = fmaf(sw1[l * L + m], sspn[vv * L + m], v);
                r[l] = v + logits[l * NVOX + i16];
            }
            if (it == ITERS - 1) {
                if (s == 0)
#pragma unroll
                    for (int l = 0; l < L; l++) out[l * NVOX + i16] = r[l];
            } else {
                float mx = -1e30f;
#pragma unroll
                for (int l = 0; l < L; l++) mx = fmaxf(mx, r[l]);
                float sum = 0.f;
#pragma unroll
                for (int l = 0; l < L; l++) { r[l] = __expf(r[l] - mx); sum += r[l]; }
                float inv = 1.f / sum;
                if (s == 0)
#pragma unroll
                    for (int l = 0; l < L; l++)
                        ustore(&q[l * NVOX + i16], r[l] * inv);   // to LLC
            }
        } else {
            // zero next iteration's A2 buffer (blocks 128..137 cover it)
            int e = (bid - 128) * TPB + tid;
            if (e < 22 * UPAD) ustore(&A2next[e], 0.f);
        }
        if (it < ITERS - 1)
            gridbar(bar, phase++, true);   // next P2 cached-reads rewritten q -> inv
    }
}

extern "C" void kernel_launch(void* const* d_in, const int* in_sizes, int n_in,
                              void* d_out, int out_size, void* d_ws, size_t ws_size,
                              hipStream_t stream) {
    const float* image  = (const float*)d_in[0];
    const float* logits = (const float*)d_in[1];
    const float* Wsp    = (const float*)d_in[2];
    const float* Wbi    = (const float*)d_in[3];
    const float* Wc     = (const float*)d_in[4];
    float* out = (float*)d_out;

    char* ws = (char*)d_ws;
    float* Phi   = (float*)ws; ws += (size_t)UPAD * NVOX * sizeof(float);    // 3.67 MB
    float* nsp   = (float*)ws; ws += (size_t)NVOX * sizeof(float);
    float* q     = (float*)ws; ws += (size_t)L * NVOX * sizeof(float);
    float* spv   = (float*)ws; ws += (size_t)L * NVOX * sizeof(float);
    float* A2    = (float*)ws; ws += (size_t)2 * 22 * UPAD * sizeof(float);  // double buffer
    float* cu    = (float*)ws; ws += (size_t)256 * sizeof(float);
    float* W1    = (float*)ws; ws += (size_t)512 * sizeof(float);
    float* W2    = (float*)ws; ws += (size_t)512 * sizeof(float);
    unsigned* bar = (unsigned*)ws; ws += (size_t)4096;  // sharded barrier state

    hipMemsetAsync(bar, 0, 4096, stream);
    hipLaunchKernelGGL(crf_fused, dim3(NBLK), dim3(TPB), 0, stream,
                       image, logits, Wsp, Wbi, Wc,
                       Phi, nsp, q, spv, A2, cu, W1, W2, bar, out);
}

// Round 6
// 198.059 us; speedup vs baseline: 1.9172x; 1.9172x over previous
//
#include <hip/hip_runtime.h>

#define L 21
#define NVOX 4096
#define ITERS 5
#define NU 210      // monomials of degree <= 4 in 6 vars
#define UPAD 224    // padded rows (210..223 are zero)
#define NBLK (NU + L)   // 231 blocks: 210 g1 + 21 spatial
#define TPB 512

// ---------------------------------------------------------------------------
// Uncached (LLC coherence-point) scalar access via builtins — compiler tracks
// data deps. Used ONLY for A2/spv (small, crosses the intra-node boundary)
// and for init-written tables (Phi/nsp/cu/W1/W2 -> immutable afterwards).
// q crosses NODE boundaries via plain cached stores (dispatch-boundary
// coherence — the always-correct path).
// ---------------------------------------------------------------------------
__device__ __forceinline__ float uload(const float* p) {
    return __hip_atomic_load(p, __ATOMIC_RELAXED, __HIP_MEMORY_SCOPE_AGENT);
}
__device__ __forceinline__ void ustore(float* p, float v) {
    __hip_atomic_store(p, v, __ATOMIC_RELAXED, __HIP_MEMORY_SCOPE_AGENT);
}

// ---------------------------------------------------------------------------
// Node AB: Phi + nsp + q0 + W-folds + cu + zero both A2 buffers. 34 blocks.
// ---------------------------------------------------------------------------
__global__ __launch_bounds__(TPB) void phase_ab(
    const float* __restrict__ img, const float* __restrict__ logits,
    const float* __restrict__ Wsp, const float* __restrict__ Wbi,
    const float* __restrict__ Wc,
    float* __restrict__ Phi, float* __restrict__ nsp, float* __restrict__ q,
    float* __restrict__ cu, float* __restrict__ W1, float* __restrict__ W2,
    float* __restrict__ A2)
{
    const int tid = threadIdx.x;
    const int bid = blockIdx.x;
    if (bid < 32) {
        // Phi builder: 128 voxels/block, 4 u-groups of 56
        const int vloc = tid & 127;
        const int w = tid >> 7;
        const int i = bid * 128 + vloc;
        const int z = i >> 8, yy = (i >> 4) & 15, xx = i & 15;
        const float ia = 1.0f / 67.0f, ib = 1.0f / 3.0f;
        float f[6];
        f[0] = (float)z * ia; f[1] = (float)yy * ia; f[2] = (float)xx * ia;
        f[3] = img[i] * ib; f[4] = img[NVOX + i] * ib; f[5] = img[2 * NVOX + i] * ib;
        float p[6][5];
#pragma unroll
        for (int c = 0; c < 6; c++) {
            p[c][0] = 1.f;
#pragma unroll
            for (int k = 1; k < 5; k++) p[c][k] = p[c][k - 1] * f[c];
        }
        float hsv = 0.5f * (f[0]*f[0] + f[1]*f[1] + f[2]*f[2] +
                            f[3]*f[3] + f[4]*f[4] + f[5]*f[5]);
        float e0 = __expf(-hsv);
        const int ulo = w * 56, uhi = ulo + 56;
        int u = 0;
        for (int a0 = 0; a0 <= 4; a0++)
        for (int a1 = 0; a1 <= 4 - a0; a1++)
        for (int a2 = 0; a2 <= 4 - a0 - a1; a2++)
        for (int a3 = 0; a3 <= 4 - a0 - a1 - a2; a3++)
        for (int a4 = 0; a4 <= 4 - a0 - a1 - a2 - a3; a4++)
        for (int a5 = 0; a5 <= 4 - a0 - a1 - a2 - a3 - a4; a5++) {
            if (u >= ulo && u < uhi)
                ustore(&Phi[(size_t)u * NVOX + i],
                       e0 * p[0][a0] * p[1][a1] * p[2][a2] * p[3][a3] * p[4][a4] * p[5][a5]);
            u++;
        }
        if (w == 3)
            for (int uz = NU; uz < UPAD; uz++)
                ustore(&Phi[(size_t)uz * NVOX + i], 0.f);
        if (w == 0) {
            float hz = 0.f, hy = 0.f, hx = 0.f;
            for (int t = 0; t < 16; t++) {
                float dz = (float)(z - t), dy = (float)(yy - t), dx = (float)(xx - t);
                hz += __expf(-0.5f * dz * dz);
                hy += __expf(-0.5f * dy * dy);
                hx += __expf(-0.5f * dx * dx);
            }
            ustore(&nsp[i], hz * hy * hx);
        }
        if (w == 1) {   // softmax of logits -> q (iteration 0); plain cached
            float vals[L]; float mx = -1e30f;
#pragma unroll
            for (int l = 0; l < L; l++) { vals[l] = logits[l * NVOX + i]; mx = fmaxf(mx, vals[l]); }
            float sum = 0.f;
#pragma unroll
            for (int l = 0; l < L; l++) { vals[l] = __expf(vals[l] - mx); sum += vals[l]; }
            float inv = 1.f / sum;
#pragma unroll
            for (int l = 0; l < L; l++) q[l * NVOX + i] = vals[l] * inv;
        }
    } else if (bid == 32) {
        for (int e = tid; e < L * L; e += TPB) {
            int r = e / L, c = e % L;
            float s1 = 0.f, s2 = 0.f;
            for (int k = 0; k < L; k++) {
                float wc = Wc[r * L + k];
                s1 = fmaf(wc, Wsp[k * L + c], s1);
                s2 = fmaf(wc, Wbi[k * L + c], s2);
            }
            ustore(&W1[e], s1); ustore(&W2[e], s2);
        }
        if (tid < 256) {
            const float invf[5] = {1.f, 1.f, 0.5f, 1.f / 6.f, 1.f / 24.f};
            float mine = 0.f;   // stays 0 for tid >= NU
            int v = 0;
            for (int a0 = 0; a0 <= 4; a0++)
            for (int a1 = 0; a1 <= 4 - a0; a1++)
            for (int a2 = 0; a2 <= 4 - a0 - a1; a2++)
            for (int a3 = 0; a3 <= 4 - a0 - a1 - a2; a3++)
            for (int a4 = 0; a4 <= 4 - a0 - a1 - a2 - a3; a4++)
            for (int a5 = 0; a5 <= 4 - a0 - a1 - a2 - a3 - a4; a5++) {
                if (v == tid)
                    mine = invf[a0] * invf[a1] * invf[a2] * invf[a3] * invf[a4] * invf[a5];
                v++;
            }
            ustore(&cu[tid], mine);
        }
    } else {
        // zero BOTH A2 double-buffers (22 rows each)
        for (int e = tid; e < 2 * 22 * UPAD; e += TPB) ustore(&A2[e], 0.f);
    }
}

// ---------------------------------------------------------------------------
// Node p23 (one per iteration): P2 roles on all 231 blocks, then an internal
// producer->consumer flag (all-relaxed; data at LLC before signal), then P3
// on blocks 0..127. q in/out via plain cached paths (node boundaries).
// ---------------------------------------------------------------------------
__global__ __launch_bounds__(TPB) void p23(
    const float* __restrict__ Phi, const float* __restrict__ nsp,
    float* __restrict__ q, float* __restrict__ spv,
    float* __restrict__ A2cur, float* __restrict__ A2next,
    const float* __restrict__ cu, const float* __restrict__ W1,
    const float* __restrict__ W2, const float* __restrict__ logits,
    unsigned* __restrict__ cnt, float* __restrict__ out, int last)
{
    __shared__ float smem[8208];   // spatial: 4096+4096+16; p3: 6041
    const int tid = threadIdx.x;
    const int bid = blockIdx.x;

    // ================= P2 roles =================
    if (bid < NU) {
        // g1 for u=bid: 8 waves x 512-voxel chunks, 22 accumulators.
        // q (written by prev node, cached) + Phi (immutable, cached).
        const int lane = tid & 63, w = tid >> 6;
        const float4* Pr = (const float4*)(Phi + (size_t)bid * NVOX) + w * 128;
        float4 pa = Pr[lane];
        float4 pb = Pr[lane + 64];
        float acc[22];
        acc[21] = pa.x + pa.y + pa.z + pa.w + pb.x + pb.y + pb.z + pb.w;
#pragma unroll
        for (int m = 0; m < L; m++) {
            const float4* Qr = (const float4*)(q + m * NVOX) + w * 128;
            float4 qa = Qr[lane];
            float4 qb = Qr[lane + 64];
            acc[m] = fmaf(qa.x, pa.x, fmaf(qa.y, pa.y, fmaf(qa.z, pa.z,
                     fmaf(qa.w, pa.w, fmaf(qb.x, pb.x, fmaf(qb.y, pb.y,
                     fmaf(qb.z, pb.z, qb.w * pb.w)))))));
        }
#pragma unroll
        for (int off = 32; off >= 1; off >>= 1)
#pragma unroll
            for (int m = 0; m < 22; m++)
                acc[m] += __shfl_xor(acc[m], off);
        if (lane < 22) {
            float val;
            if (lane < L) {
                float dot = 0.f;
#pragma unroll
                for (int m = 0; m < L; m++)
                    dot = fmaf(W2[lane * L + m], acc[m], dot);
                val = cu[bid] * dot;
            } else {
                val = cu[bid] * acc[21];
            }
            atomicAdd(&A2cur[lane * UPAD + bid], val);   // device-scope, at LLC
        }
        // blocks 128..137 also zero next iteration's A2 (tiny; pre-signal)
        if (bid >= 128 && bid < 138) {
            int e = (bid - 128) * TPB + tid;
            if (e < 22 * UPAD) ustore(&A2next[e], 0.f);
        }
    } else {
        // spatial filter for label l = bid - NU (exact separable 16-tap)
        const int l = bid - NU;
        float* buf = smem;
        float* tmp = smem + 4096;
        float* g   = smem + 8192;
        if (tid < 16) g[tid] = __expf(-0.5f * (float)(tid * tid));
        for (int k = 0; k < 8; k++)
            buf[tid + TPB * k] = q[l * NVOX + tid + TPB * k];   // cached
        __syncthreads();
        for (int k = 0; k < 8; k++) {
            int idx = tid + TPB * k;
            int x = idx & 15, base = idx & ~15;
            float ssum = 0.f;
#pragma unroll
            for (int t = 0; t < 16; t++) {
                int d = x - t; d = d < 0 ? -d : d;
                ssum += g[d] * buf[base + t];
            }
            tmp[idx] = ssum;
        }
        __syncthreads();
        for (int k = 0; k < 8; k++) {
            int idx = tid + TPB * k;
            int y = (idx >> 4) & 15, base = idx & ~(15 << 4);
            float ssum = 0.f;
#pragma unroll
            for (int t = 0; t < 16; t++) {
                int d = y - t; d = d < 0 ? -d : d;
                ssum += g[d] * tmp[base + (t << 4)];
            }
            buf[idx] = ssum;
        }
        __syncthreads();
        for (int k = 0; k < 8; k++) {
            int idx = tid + TPB * k;
            int z = idx >> 8, base = idx & 255;
            float ssum = 0.f;
#pragma unroll
            for (int t = 0; t < 16; t++) {
                int d = z - t; d = d < 0 ? -d : d;
                ssum += g[d] * buf[base + (t << 8)];
            }
            ustore(&spv[l * NVOX + idx], ssum);   // write-through to LLC
        }
    }

    // ---- signal: every wave drains its vmem (A2 atomics / spv stores are
    // then complete at the LLC), then one relaxed count per block ----
    asm volatile("s_waitcnt vmcnt(0) lgkmcnt(0)" ::: "memory");
    __syncthreads();
    if (tid == 0)
        __hip_atomic_fetch_add(cnt, 1u, __ATOMIC_RELAXED,
                               __HIP_MEMORY_SCOPE_AGENT);
    if (bid >= 128) return;   // producers-only blocks exit

    // ---- consumer wait: all 231 blocks' data at LLC ----
    if (tid == 0) {
        while (__hip_atomic_load(cnt, __ATOMIC_RELAXED,
                                 __HIP_MEMORY_SCOPE_AGENT) < (unsigned)NBLK)
            __builtin_amdgcn_s_sleep(2);
        asm volatile("" ::: "memory");
    }
    __syncthreads();

    // ================= P3 (blocks 0..127, 32 voxels each) =================
    {
        float* sA   = smem;                 // 21*224 = 4704
        float* sN   = smem + 4704;          // 224
        float* sw1  = smem + 4928;          // 441
        float* sspn = smem + 5369;          // 32*21 = 672, layout [v][m]
        const int vv = tid >> 4;            // 0..31 voxels
        const int s  = tid & 15;            // 0..15 u-splits (in-wave)
        const int i16 = bid * 32 + vv;
        for (int e = tid; e < L * UPAD; e += TPB) sA[e] = uload(&A2cur[e]);
        for (int e = tid; e < UPAD; e += TPB) sN[e] = uload(&A2cur[L * UPAD + e]);
        for (int e = tid; e < L * L; e += TPB) sw1[e] = W1[e];       // cached
        for (int e = tid; e < 32 * L; e += TPB) {
            int m = e >> 5, v2 = e & 31;
            sspn[v2 * L + m] = uload(&spv[m * NVOX + bid * 32 + v2])
                               / nsp[bid * 32 + v2];                 // nsp cached
        }
        __syncthreads();
        float acc[22];
#pragma unroll
        for (int m = 0; m < 22; m++) acc[m] = 0.f;
        const int u0 = s * 14;
        for (int uu = 0; uu < 14; uu++) {
            float pv = Phi[(size_t)(u0 + uu) * NVOX + i16];   // cached
#pragma unroll
            for (int m = 0; m < L; m++)
                acc[m] = fmaf(sA[m * UPAD + u0 + uu], pv, acc[m]);
            acc[21] = fmaf(sN[u0 + uu], pv, acc[21]);
        }
        // butterfly allreduce across the 16 u-splits (within wave)
#pragma unroll
        for (int off = 1; off <= 8; off <<= 1)
#pragma unroll
            for (int m = 0; m < 22; m++)
                acc[m] += __shfl_xor(acc[m], off);
        float rbi = 1.f / acc[21];
        float r[L];
#pragma unroll
        for (int l = 0; l < L; l++) {
            float v = acc[l] * rbi;
#pragma unroll
            for (int m = 0; m < L; m++)
                v = fmaf(sw1[l * L + m], sspn[vv * L + m], v);
            r[l] = v + logits[l * NVOX + i16];
        }
        if (last) {
            if (s == 0)
#pragma unroll
                for (int l = 0; l < L; l++) out[l * NVOX + i16] = r[l];
        } else {
            float mx = -1e30f;
#pragma unroll
            for (int l = 0; l < L; l++) mx = fmaxf(mx, r[l]);
            float sum = 0.f;
#pragma unroll
            for (int l = 0; l < L; l++) { r[l] = __expf(r[l] - mx); sum += r[l]; }
            float inv = 1.f / sum;
            if (s == 0)
#pragma unroll
                for (int l = 0; l < L; l++)
                    q[l * NVOX + i16] = r[l] * inv;   // plain cached; next node
        }
    }
}

extern "C" void kernel_launch(void* const* d_in, const int* in_sizes, int n_in,
                              void* d_out, int out_size, void* d_ws, size_t ws_size,
                              hipStream_t stream) {
    const float* image  = (const float*)d_in[0];
    const float* logits = (const float*)d_in[1];
    const float* Wsp    = (const float*)d_in[2];
    const float* Wbi    = (const float*)d_in[3];
    const float* Wc     = (const float*)d_in[4];
    float* out = (float*)d_out;

    char* ws = (char*)d_ws;
    float* Phi   = (float*)ws; ws += (size_t)UPAD * NVOX * sizeof(float);    // 3.67 MB
    float* nsp   = (float*)ws; ws += (size_t)NVOX * sizeof(float);
    float* q     = (float*)ws; ws += (size_t)L * NVOX * sizeof(float);
    float* spv   = (float*)ws; ws += (size_t)L * NVOX * sizeof(float);
    float* A2    = (float*)ws; ws += (size_t)2 * 22 * UPAD * sizeof(float);  // double buffer
    float* cu    = (float*)ws; ws += (size_t)256 * sizeof(float);
    float* W1    = (float*)ws; ws += (size_t)512 * sizeof(float);
    float* W2    = (float*)ws; ws += (size_t)512 * sizeof(float);
    unsigned* flags = (unsigned*)ws; ws += (size_t)1024;  // one counter / iter

    hipMemsetAsync(flags, 0, 1024, stream);
    hipLaunchKernelGGL(phase_ab, dim3(34), dim3(TPB), 0, stream,
                       image, logits, Wsp, Wbi, Wc, Phi, nsp, q, cu, W1, W2, A2);
    for (int it = 0; it < ITERS; it++) {
        float* A2cur  = A2 + (it & 1) * 22 * UPAD;
        float* A2next = A2 + ((it + 1) & 1) * 22 * UPAD;
        hipLaunchKernelGGL(p23, dim3(NBLK), dim3(TPB), 0, stream,
                           Phi, nsp, q, spv, A2cur, A2next, cu, W1, W2,
                           logits, flags + it * 32, out,
                           it == ITERS - 1 ? 1 : 0);
    }
}